// Round 6
// baseline (940.616 us; speedup 1.0000x reference)
//
#include <hip/hip_runtime.h>
#include <math.h>

#define NN 50000
#define NE 800000

typedef __attribute__((ext_vector_type(8))) short bh8;   // 8 bf16 = 4 VGPR (MFMA A/B frag)
typedef __attribute__((ext_vector_type(4))) float fx4;   // MFMA C/D frag

__device__ __forceinline__ short f2b(float x) {
    union { float f; unsigned u; } a; a.f = x;
    unsigned r = a.u + 0x7FFF + ((a.u >> 16) & 1);   // round-to-nearest-even
    return (short)(r >> 16);
}
__device__ __forceinline__ float b2f(short s) {
    union { unsigned u; float f; } a; a.u = ((unsigned)(unsigned short)s) << 16;
    return a.f;
}
__device__ __forceinline__ float sigm(float x) { return 1.f / (1.f + __expf(-x)); }

// ---------------- prep ----------------
// wf[0:64]=A(Pin), wf[64:128]=B(Pout), wf[128:192]=C(J)
__global__ __launch_bounds__(64) void prep_wf(const float* __restrict__ W1,
                                              float* __restrict__ wf)
{
    int j = threadIdx.x;
    wf[j]       = W1[64 * 64 + j]  - W1[65 * 64 + j];
    wf[64 + j]  = W1[133 * 64 + j] - W1[132 * 64 + j];
    wf[128 + j] = W1[66 * 64 + j] - W1[67 * 64 + j]
                - W1[134 * 64 + j] + W1[135 * 64 + j];
}

// W2tB[c*64+k] = bf16(W2[k*64+c]); same for W3
__global__ __launch_bounds__(256) void prep_w23(const float* __restrict__ W2,
                                                const float* __restrict__ W3,
                                                short* __restrict__ W2tB,
                                                short* __restrict__ W3tB)
{
    int i = blockIdx.x * 256 + threadIdx.x;
    if (i < 4096) {
        int c = i >> 6, k = i & 63;
        W2tB[i] = f2b(W2[k * 64 + c]);
        W3tB[i] = f2b(W3[k * 64 + c]);
    }
}

__global__ __launch_bounds__(256) void init_state(
    const float* __restrict__ b, const float* __restrict__ W_in,
    const float* __restrict__ b_in,
    float* __restrict__ state, float* __restrict__ agg)
{
    int idx = blockIdx.x * 256 + threadIdx.x;
    if (idx >= NN * 64) return;
    int n = idx >> 6, j = idx & 63;
    state[idx] = b[n] * (W_in[j] - W_in[64 + j]) + b_in[j];
    agg[idx] = 0.f;
}

// ---------------- CSR build ----------------
__global__ __launch_bounds__(256) void csr_zero(int* __restrict__ cnt, int* __restrict__ cur)
{
    int i = blockIdx.x * 256 + threadIdx.x;
    if (i < NN) { cnt[i] = 0; cur[i] = 0; }
}

__global__ __launch_bounds__(256) void csr_count(const int* __restrict__ mn, int* __restrict__ cnt)
{
    int e = blockIdx.x * 256 + threadIdx.x;
    if (e < NE) atomicAdd(&cnt[mn[2 * e + 1]], 1);
}

__global__ __launch_bounds__(256) void scan_block(const int* __restrict__ cnt,
                                                  int* __restrict__ base, int* __restrict__ bsum)
{
    __shared__ int s[256];
    int i = blockIdx.x * 256 + threadIdx.x;
    int v = (i < NN) ? cnt[i] : 0;
    s[threadIdx.x] = v;
    __syncthreads();
    for (int off = 1; off < 256; off <<= 1) {
        int t = (threadIdx.x >= off) ? s[threadIdx.x - off] : 0;
        __syncthreads();
        s[threadIdx.x] += t;
        __syncthreads();
    }
    if (i < NN) base[i] = s[threadIdx.x] - v;
    if (threadIdx.x == 255) bsum[blockIdx.x] = s[255];
}

__global__ __launch_bounds__(256) void scan_top(int* __restrict__ bsum, int nb)
{
    __shared__ int s[256];
    int t = threadIdx.x;
    int v = (t < nb) ? bsum[t] : 0;
    s[t] = v;
    __syncthreads();
    for (int off = 1; off < 256; off <<= 1) {
        int u = (t >= off) ? s[t - off] : 0;
        __syncthreads();
        s[t] += u;
        __syncthreads();
    }
    if (t < nb) bsum[t] = s[t] - v;
}

__global__ __launch_bounds__(256) void scan_add(int* __restrict__ base, const int* __restrict__ bsum)
{
    int i = blockIdx.x * 256 + threadIdx.x;
    if (i < NN) base[i] += bsum[blockIdx.x];
}

__global__ __launch_bounds__(256) void csr_scatter_perm(const int* __restrict__ mn,
    const float* __restrict__ Jm,
    const int* __restrict__ base, int* __restrict__ cur,
    int* __restrict__ einP, int* __restrict__ eoutP, float* __restrict__ JP)
{
    int e = blockIdx.x * 256 + threadIdx.x;
    if (e < NE) {
        int n = mn[2 * e + 1];
        int p = base[n] + atomicAdd(&cur[n], 1);
        einP[p]  = mn[2 * e];
        eoutP[p] = n;
        JP[p]    = Jm[e];
    }
}

#define FMA16(xv, wv)                                                        \
    acc[0][0] += xv.x * wv.x; acc[0][1] += xv.x * wv.y;                      \
    acc[0][2] += xv.x * wv.z; acc[0][3] += xv.x * wv.w;                      \
    acc[1][0] += xv.y * wv.x; acc[1][1] += xv.y * wv.y;                      \
    acc[1][2] += xv.y * wv.z; acc[1][3] += xv.y * wv.w;                      \
    acc[2][0] += xv.z * wv.x; acc[2][1] += xv.z * wv.y;                      \
    acc[2][2] += xv.z * wv.z; acc[2][3] += xv.z * wv.w;                      \
    acc[3][0] += xv.w * wv.x; acc[3][1] += xv.w * wv.y;                      \
    acc[3][2] += xv.w * wv.z; acc[3][3] += xv.w * wv.w;

// ---------------- per-node layer-1 projections (fp32) ----------------
// ct=0: Pin = state@W1[0:64]   + b*A + b1
// ct=1: Pout= state@W1[68:132] + b*B
__global__ __launch_bounds__(256, 2) void node_proj(
    const float* __restrict__ state, const float* __restrict__ bb,
    const float* __restrict__ W1, const float* __restrict__ wf,
    const float* __restrict__ b1,
    float* __restrict__ Pin, float* __restrict__ Pout)
{
    __shared__ float xh[64][68];
    __shared__ float ws[64][64];
    __shared__ float sb[64];

    int tid = threadIdx.x;
    int ct = blockIdx.x & 1;
    int n0 = (blockIdx.x >> 1) * 64;

    const float* Wbase = W1 + (ct ? 68 * 64 : 0);
    float* P = ct ? Pout : Pin;

    {
        int m = tid & 63, cc = tid >> 6;
        int n = n0 + m;
        bool ok = (n < NN);
#pragma unroll
        for (int r = 0; r < 4; r++) {
            int k = cc * 4 + r * 16;
            float4 v = ok ? *(const float4*)&state[(size_t)n * 64 + k]
                          : make_float4(0.f, 0.f, 0.f, 0.f);
            xh[k + 0][m] = v.x; xh[k + 1][m] = v.y; xh[k + 2][m] = v.z; xh[k + 3][m] = v.w;
        }
        const float4* wsrc = (const float4*)Wbase;
        float4* wdst = (float4*)ws;
#pragma unroll
        for (int r = 0; r < 4; r++) wdst[tid + 256 * r] = wsrc[tid + 256 * r];
        if (tid < 64) sb[tid] = (n0 + tid < NN) ? bb[n0 + tid] : 0.f;
    }
    __syncthreads();

    int tn4 = (tid & 15) * 4, tm4 = (tid >> 4) * 4;
    float acc[4][4];
#pragma unroll
    for (int i = 0; i < 4; i++)
#pragma unroll
        for (int j = 0; j < 4; j++) acc[i][j] = 0.f;

#pragma unroll 8
    for (int k = 0; k < 64; k++) {
        float4 xv = *(const float4*)&xh[k][tm4];
        float4 wv = *(const float4*)&ws[k][tn4];
        FMA16(xv, wv)
    }

    float4 Fv = *(const float4*)&wf[ct * 64 + tn4];
    float4 Bv = ct ? make_float4(0.f, 0.f, 0.f, 0.f) : *(const float4*)&b1[tn4];
    float F[4] = {Fv.x, Fv.y, Fv.z, Fv.w};
    float Bi[4] = {Bv.x, Bv.y, Bv.z, Bv.w};
#pragma unroll
    for (int i = 0; i < 4; i++) {
        int n = n0 + tm4 + i;
        if (n < NN) {
            float bn = sb[tm4 + i];
            float4 v;
            v.x = acc[i][0] + bn * F[0] + Bi[0];
            v.y = acc[i][1] + bn * F[1] + Bi[1];
            v.z = acc[i][2] + bn * F[2] + Bi[2];
            v.w = acc[i][3] + bn * F[3] + Bi[3];
            *(float4*)&P[(size_t)n * 64 + tn4] = v;
        }
    }
}

// ---------------- edge MLP (layers 2+3) + fused segment-sum ----------------
// 64 CSR-ordered edges x 64 cols per block; 4 waves, wave w owns band [16w,16w+16).
// h1/h2 f32 in LDS; A split hi+lo (only W2/W3 bf16 rounding remains).
// After GEMM3: in-block run reduction over equal eout; interior runs -> plain
// float4 stores (exclusive owner, agg pre-zeroed); boundary runs -> atomicAdd.
__global__ __launch_bounds__(256, 3) void edge_msg_mfma(
    const int* __restrict__ einP, const int* __restrict__ eoutP,
    const float* __restrict__ JP,
    const float* __restrict__ Pin, const float* __restrict__ Pout,
    const float* __restrict__ wf,
    const short* __restrict__ W2tB, const float* __restrict__ b2,
    const short* __restrict__ W3tB, const float* __restrict__ b3,
    float* __restrict__ agg)
{
    __shared__ float h1f[64][68];   // h1 f32 (later reused for m output)
    __shared__ float h2f[64][68];   // h2 f32
    __shared__ short w2s[64][72];   // W2^T [col][k] bf16
    __shared__ short w3s[64][72];   // W3^T [col][k] bf16
    __shared__ int   seo[64];

    int tid = threadIdx.x;
    int p0 = blockIdx.x * 64;

    // ---- stage: h1 = relu(Pin[a] + Pout[o] + J*C) f32 -> LDS; W2t/W3t -> LDS ----
    {
        if (tid < 64) seo[tid] = eoutP[p0 + tid];
        int m = tid & 63, kb = (tid >> 6) * 16;
        int a = einP[p0 + m], o = eoutP[p0 + m];
        float J = JP[p0 + m];
#pragma unroll
        for (int q = 0; q < 4; q++) {
            float4 va = *(const float4*)&Pin[(size_t)a * 64 + kb + 4 * q];
            float4 vo = *(const float4*)&Pout[(size_t)o * 64 + kb + 4 * q];
            float4 vc = *(const float4*)&wf[128 + kb + 4 * q];
            float4 r;
            r.x = fmaxf(va.x + vo.x + J * vc.x, 0.f);
            r.y = fmaxf(va.y + vo.y + J * vc.y, 0.f);
            r.z = fmaxf(va.z + vo.z + J * vc.z, 0.f);
            r.w = fmaxf(va.w + vo.w + J * vc.w, 0.f);
            *(float4*)&h1f[m][kb + 4 * q] = r;
        }
        int row = tid >> 2, cb = (tid & 3) * 16;
        *(bh8*)&w2s[row][cb]     = *(const bh8*)&W2tB[row * 64 + cb];
        *(bh8*)&w2s[row][cb + 8] = *(const bh8*)&W2tB[row * 64 + cb + 8];
        *(bh8*)&w3s[row][cb]     = *(const bh8*)&W3tB[row * 64 + cb];
        *(bh8*)&w3s[row][cb + 8] = *(const bh8*)&W3tB[row * 64 + cb + 8];
    }
    __syncthreads();

    int w = tid >> 6, l = tid & 63;
    int lr = l & 15, lg = l >> 4;

    float b2v[4], b3v[4];
#pragma unroll
    for (int ct = 0; ct < 4; ct++) { b2v[ct] = b2[ct * 16 + lr]; b3v[ct] = b3[ct * 16 + lr]; }

    // ---- GEMM2: h2 = relu(h1 @ W2 + b2), A split hi+lo ----
    {
        float va[8], vb[8];
        *(float4*)&va[0] = *(const float4*)&h1f[16 * w + lr][lg * 8];
        *(float4*)&va[4] = *(const float4*)&h1f[16 * w + lr][lg * 8 + 4];
        *(float4*)&vb[0] = *(const float4*)&h1f[16 * w + lr][lg * 8 + 32];
        *(float4*)&vb[4] = *(const float4*)&h1f[16 * w + lr][lg * 8 + 36];
        bh8 Ahi1, Alo1, Ahi2, Alo2;
#pragma unroll
        for (int j = 0; j < 8; j++) {
            short h = f2b(va[j]); Ahi1[j] = h; Alo1[j] = f2b(va[j] - b2f(h));
            short g = f2b(vb[j]); Ahi2[j] = g; Alo2[j] = f2b(vb[j] - b2f(g));
        }
#pragma unroll
        for (int ct = 0; ct < 4; ct++) {
            bh8 B1 = *(const bh8*)&w2s[16 * ct + lr][lg * 8];
            bh8 B2 = *(const bh8*)&w2s[16 * ct + lr][lg * 8 + 32];
            fx4 acc = {0.f, 0.f, 0.f, 0.f};
            acc = __builtin_amdgcn_mfma_f32_16x16x32_bf16(Ahi1, B1, acc, 0, 0, 0);
            acc = __builtin_amdgcn_mfma_f32_16x16x32_bf16(Alo1, B1, acc, 0, 0, 0);
            acc = __builtin_amdgcn_mfma_f32_16x16x32_bf16(Ahi2, B2, acc, 0, 0, 0);
            acc = __builtin_amdgcn_mfma_f32_16x16x32_bf16(Alo2, B2, acc, 0, 0, 0);
#pragma unroll
            for (int r = 0; r < 4; r++)
                h2f[16 * w + 4 * lg + r][16 * ct + lr] = fmaxf(acc[r] + b2v[ct], 0.f);
        }
    }

    // ---- GEMM3: m = h2 @ W3 + b3 (band-private through LDS) ----
    {
        float va[8], vb[8];
        *(float4*)&va[0] = *(const float4*)&h2f[16 * w + lr][lg * 8];
        *(float4*)&va[4] = *(const float4*)&h2f[16 * w + lr][lg * 8 + 4];
        *(float4*)&vb[0] = *(const float4*)&h2f[16 * w + lr][lg * 8 + 32];
        *(float4*)&vb[4] = *(const float4*)&h2f[16 * w + lr][lg * 8 + 36];
        bh8 Chi1, Clo1, Chi2, Clo2;
#pragma unroll
        for (int j = 0; j < 8; j++) {
            short h = f2b(va[j]); Chi1[j] = h; Clo1[j] = f2b(va[j] - b2f(h));
            short g = f2b(vb[j]); Chi2[j] = g; Clo2[j] = f2b(vb[j] - b2f(g));
        }
#pragma unroll
        for (int ct = 0; ct < 4; ct++) {
            bh8 B1 = *(const bh8*)&w3s[16 * ct + lr][lg * 8];
            bh8 B2 = *(const bh8*)&w3s[16 * ct + lr][lg * 8 + 32];
            fx4 acc = {0.f, 0.f, 0.f, 0.f};
            acc = __builtin_amdgcn_mfma_f32_16x16x32_bf16(Chi1, B1, acc, 0, 0, 0);
            acc = __builtin_amdgcn_mfma_f32_16x16x32_bf16(Clo1, B1, acc, 0, 0, 0);
            acc = __builtin_amdgcn_mfma_f32_16x16x32_bf16(Chi2, B2, acc, 0, 0, 0);
            acc = __builtin_amdgcn_mfma_f32_16x16x32_bf16(Clo2, B2, acc, 0, 0, 0);
#pragma unroll
            for (int r = 0; r < 4; r++)
                h1f[16 * w + 4 * lg + r][16 * ct + lr] = acc[r] + b3v[ct];   // m -> own band
        }
    }

    __syncthreads();   // all bands' m visible

    // ---- fused segment-sum over CSR runs ----
    {
        int r  = tid >> 2;            // edge row 0..63
        int c4 = (tid & 3) << 4;      // col base {0,16,32,48}
        int n  = seo[r];
        bool head = (r == 0) || (seo[r - 1] != n);
        if (head) {
            int end = r + 1;
            while (end < 64 && seo[end] == n) end++;
            float4 a0 = *(const float4*)&h1f[r][c4];
            float4 a1 = *(const float4*)&h1f[r][c4 + 4];
            float4 a2 = *(const float4*)&h1f[r][c4 + 8];
            float4 a3 = *(const float4*)&h1f[r][c4 + 12];
            for (int rr = r + 1; rr < end; rr++) {
                float4 v0 = *(const float4*)&h1f[rr][c4];
                float4 v1 = *(const float4*)&h1f[rr][c4 + 4];
                float4 v2 = *(const float4*)&h1f[rr][c4 + 8];
                float4 v3 = *(const float4*)&h1f[rr][c4 + 12];
                a0.x += v0.x; a0.y += v0.y; a0.z += v0.z; a0.w += v0.w;
                a1.x += v1.x; a1.y += v1.y; a1.z += v1.z; a1.w += v1.w;
                a2.x += v2.x; a2.y += v2.y; a2.z += v2.z; a2.w += v2.w;
                a3.x += v3.x; a3.y += v3.y; a3.z += v3.z; a3.w += v3.w;
            }
            float* ar = agg + (size_t)n * 64 + c4;
            if (r > 0 && end < 64) {
                // interior run: this block owns ALL of node n's edges
                *(float4*)&ar[0]  = a0;
                *(float4*)&ar[4]  = a1;
                *(float4*)&ar[8]  = a2;
                *(float4*)&ar[12] = a3;
            } else {
                atomicAdd(ar + 0,  a0.x); atomicAdd(ar + 1,  a0.y);
                atomicAdd(ar + 2,  a0.z); atomicAdd(ar + 3,  a0.w);
                atomicAdd(ar + 4,  a1.x); atomicAdd(ar + 5,  a1.y);
                atomicAdd(ar + 6,  a1.z); atomicAdd(ar + 7,  a1.w);
                atomicAdd(ar + 8,  a2.x); atomicAdd(ar + 9,  a2.y);
                atomicAdd(ar + 10, a2.z); atomicAdd(ar + 11, a2.w);
                atomicAdd(ar + 12, a3.x); atomicAdd(ar + 13, a3.y);
                atomicAdd(ar + 14, a3.z); atomicAdd(ar + 15, a3.w);
            }
        }
    }
}

// ---------------- GRU ----------------
__global__ __launch_bounds__(256, 2) void gru_gemm(
    const float* __restrict__ agg, const float* __restrict__ state,
    const float* __restrict__ Wih, const float* __restrict__ Whh,
    float* __restrict__ gi, float* __restrict__ gh)
{
    __shared__ float xa[64][64];
    __shared__ float xh[64][64];
    __shared__ float wi[64][64];
    __shared__ float wh[64][64];

    int tid = threadIdx.x;
    int tile = blockIdx.x / 3, ct = blockIdx.x % 3;
    int n0 = tile * 64, c0 = ct * 64;

    {
        int m = tid & 63, c = tid >> 6;
        int n = n0 + m;
        bool ok = (n < NN);
#pragma unroll
        for (int r = 0; r < 4; r++) {
            int k = c * 4 + r * 16;
            float4 v = ok ? *(const float4*)&agg[(size_t)n * 64 + k]
                          : make_float4(0.f, 0.f, 0.f, 0.f);
            xa[k + 0][m] = v.x; xa[k + 1][m] = v.y; xa[k + 2][m] = v.z; xa[k + 3][m] = v.w;
            float4 u = ok ? *(const float4*)&state[(size_t)n * 64 + k]
                          : make_float4(0.f, 0.f, 0.f, 0.f);
            xh[k + 0][m] = u.x; xh[k + 1][m] = u.y; xh[k + 2][m] = u.z; xh[k + 3][m] = u.w;
        }
#pragma unroll
        for (int r = 0; r < 4; r++) {
            int idx = tid + 256 * r;
            int k = idx >> 4, q = (idx & 15) * 4;
            *(float4*)&wi[k][q] = *(const float4*)&Wih[(size_t)k * 192 + c0 + q];
            *(float4*)&wh[k][q] = *(const float4*)&Whh[(size_t)k * 192 + c0 + q];
        }
    }
    __syncthreads();

    int tn4 = (tid & 15) * 4, tm4 = (tid >> 4) * 4;
    float ai[4][4], ah[4][4];
#pragma unroll
    for (int i = 0; i < 4; i++)
#pragma unroll
        for (int j = 0; j < 4; j++) { ai[i][j] = 0.f; ah[i][j] = 0.f; }

#pragma unroll 4
    for (int k = 0; k < 64; k++) {
        float4 av = *(const float4*)&xa[k][tm4];
        float4 hv = *(const float4*)&xh[k][tm4];
        float4 iv = *(const float4*)&wi[k][tn4];
        float4 vv = *(const float4*)&wh[k][tn4];
        ai[0][0] += av.x * iv.x; ai[0][1] += av.x * iv.y; ai[0][2] += av.x * iv.z; ai[0][3] += av.x * iv.w;
        ai[1][0] += av.y * iv.x; ai[1][1] += av.y * iv.y; ai[1][2] += av.y * iv.z; ai[1][3] += av.y * iv.w;
        ai[2][0] += av.z * iv.x; ai[2][1] += av.z * iv.y; ai[2][2] += av.z * iv.z; ai[2][3] += av.z * iv.w;
        ai[3][0] += av.w * iv.x; ai[3][1] += av.w * iv.y; ai[3][2] += av.w * iv.z; ai[3][3] += av.w * iv.w;
        ah[0][0] += hv.x * vv.x; ah[0][1] += hv.x * vv.y; ah[0][2] += hv.x * vv.z; ah[0][3] += hv.x * vv.w;
        ah[1][0] += hv.y * vv.x; ah[1][1] += hv.y * vv.y; ah[1][2] += hv.y * vv.z; ah[1][3] += hv.y * vv.w;
        ah[2][0] += hv.z * vv.x; ah[2][1] += hv.z * vv.y; ah[2][2] += hv.z * vv.z; ah[2][3] += hv.z * vv.w;
        ah[3][0] += hv.w * vv.x; ah[3][1] += hv.w * vv.y; ah[3][2] += hv.w * vv.z; ah[3][3] += hv.w * vv.w;
    }

#pragma unroll
    for (int i = 0; i < 4; i++) {
        int n = n0 + tm4 + i;
        if (n < NN) {
            float4 v; v.x = ai[i][0]; v.y = ai[i][1]; v.z = ai[i][2]; v.w = ai[i][3];
            *(float4*)&gi[(size_t)n * 192 + c0 + tn4] = v;
            float4 u; u.x = ah[i][0]; u.y = ah[i][1]; u.z = ah[i][2]; u.w = ah[i][3];
            *(float4*)&gh[(size_t)n * 192 + c0 + tn4] = u;
        }
    }
}

// also re-zeroes agg for the next propagation step
__global__ __launch_bounds__(256) void gru_gate(
    const float* __restrict__ gi, const float* __restrict__ gh,
    const float* __restrict__ bih, const float* __restrict__ bhh,
    float* __restrict__ state, float* __restrict__ agg)
{
    int t = blockIdx.x * 256 + threadIdx.x;
    int n = t >> 6;
    if (n >= NN) return;
    int j = t & 63;
    size_t gb = (size_t)n * 192;
    float ir = gi[gb + j] + bih[j];
    float iz = gi[gb + 64 + j] + bih[64 + j];
    float in_ = gi[gb + 128 + j] + bih[128 + j];
    float hr = gh[gb + j] + bhh[j];
    float hz = gh[gb + 64 + j] + bhh[64 + j];
    float hn = gh[gb + 128 + j] + bhh[128 + j];
    float r = sigm(ir + hr);
    float z = sigm(iz + hz);
    float ng = tanhf(in_ + r * hn);
    size_t si = (size_t)n * 64 + j;
    float h = state[si];
    state[si] = (1.f - z) * ng + z * h;
    agg[si] = 0.f;
}

__global__ __launch_bounds__(256) void out_proj(
    const float* __restrict__ state, const float* __restrict__ Wout,
    const float* __restrict__ bout, float* __restrict__ out)
{
    int n = blockIdx.x * 256 + threadIdx.x;
    if (n >= NN) return;
    float a0 = bout[0], a1 = bout[1];
    const float4* sr = (const float4*)(state + (size_t)n * 64);
#pragma unroll
    for (int t = 0; t < 16; t++) {
        float4 v = sr[t];
        a0 += v.x * Wout[2 * (4 * t + 0)] + v.y * Wout[2 * (4 * t + 1)]
            + v.z * Wout[2 * (4 * t + 2)] + v.w * Wout[2 * (4 * t + 3)];
        a1 += v.x * Wout[2 * (4 * t + 0) + 1] + v.y * Wout[2 * (4 * t + 1) + 1]
            + v.z * Wout[2 * (4 * t + 2) + 1] + v.w * Wout[2 * (4 * t + 3) + 1];
    }
    out[2 * n] = a0;
    out[2 * n + 1] = a1;
}

extern "C" void kernel_launch(void* const* d_in, const int* in_sizes, int n_in,
                              void* d_out, int out_size, void* d_ws, size_t ws_size,
                              hipStream_t stream)
{
    const int*   msg_node = (const int*)  d_in[0];
    const float* J_msg    = (const float*)d_in[1];
    const float* b        = (const float*)d_in[2];
    const float* W_in     = (const float*)d_in[4];
    const float* b_in     = (const float*)d_in[5];
    const float* W1       = (const float*)d_in[6];
    const float* b1       = (const float*)d_in[7];
    const float* W2       = (const float*)d_in[8];
    const float* b2       = (const float*)d_in[9];
    const float* W3       = (const float*)d_in[10];
    const float* b3       = (const float*)d_in[11];
    const float* W_ih     = (const float*)d_in[12];
    const float* b_ih     = (const float*)d_in[13];
    const float* W_hh     = (const float*)d_in[14];
    const float* b_hh     = (const float*)d_in[15];
    const float* W_out    = (const float*)d_in[16];
    const float* b_out    = (const float*)d_in[17];

    float* f     = (float*)d_ws;
    float* state = f;                                  // NN*64 f32
    float* agg   = state + (size_t)NN * 64;            // NN*64 f32
    float* Pin   = agg   + (size_t)NN * 64;            // NN*64 f32
    float* Pout  = Pin   + (size_t)NN * 64;            // NN*64 f32
    float* wf    = Pout  + (size_t)NN * 64;            // 192
    float* JP    = wf + 192;                           // NE
    int*   einP  = (int*)(JP + NE);                    // NE
    int*   eoutP = einP + NE;                          // NE
    int*   cbase = eoutP + NE;                         // NN
    int*   ccnt  = cbase + NN;                         // NN
    int*   ccur  = ccnt + NN;                          // NN
    int*   cbsum = ccur + NN;                          // 512
    short* W2tB  = (short*)(cbsum + 512);              // 4096 bf16
    short* W3tB  = W2tB + 4096;                        // 4096 bf16
    float* gi    = (float*)(W3tB + 4096);              // NN*192 f32
    float* gh    = gi + (size_t)NN * 192;              // NN*192 f32

    float* out = (float*)d_out;

    prep_wf<<<1, 64, 0, stream>>>(W1, wf);
    prep_w23<<<16, 256, 0, stream>>>(W2, W3, W2tB, W3tB);
    init_state<<<(NN * 64 + 255) / 256, 256, 0, stream>>>(b, W_in, b_in, state, agg);

    csr_zero<<<(NN + 255) / 256, 256, 0, stream>>>(ccnt, ccur);
    csr_count<<<(NE + 255) / 256, 256, 0, stream>>>(msg_node, ccnt);
    scan_block<<<(NN + 255) / 256, 256, 0, stream>>>(ccnt, cbase, cbsum);
    scan_top<<<1, 256, 0, stream>>>(cbsum, (NN + 255) / 256);
    scan_add<<<(NN + 255) / 256, 256, 0, stream>>>(cbase, cbsum);
    csr_scatter_perm<<<(NE + 255) / 256, 256, 0, stream>>>(msg_node, J_msg, cbase, ccur,
                                                           einP, eoutP, JP);

    int ntile = (NN + 63) / 64;
    for (int p = 0; p < 3; p++) {
        node_proj<<<ntile * 2, 256, 0, stream>>>(state, b, W1, wf, b1, Pin, Pout);
        edge_msg_mfma<<<NE / 64, 256, 0, stream>>>(einP, eoutP, JP, Pin, Pout, wf,
                                                   W2tB, b2, W3tB, b3, agg);
        gru_gemm<<<ntile * 3, 256, 0, stream>>>(agg, state, W_ih, W_hh, gi, gh);
        gru_gate<<<(NN * 64 + 255) / 256, 256, 0, stream>>>(gi, gh, b_ih, b_hh,
                                                            state, agg);
    }
    out_proj<<<(NN + 255) / 256, 256, 0, stream>>>(state, W_out, b_out, out);
}

// Round 7
// 921.620 us; speedup vs baseline: 1.0206x; 1.0206x over previous
//
#include <hip/hip_runtime.h>
#include <math.h>

#define NN 50000
#define NE 800000

typedef __attribute__((ext_vector_type(8))) short bh8;   // 8 bf16 = 4 VGPR (MFMA A/B frag)
typedef __attribute__((ext_vector_type(4))) float fx4;   // MFMA C/D frag

__device__ __forceinline__ short f2b(float x) {
    union { float f; unsigned u; } a; a.f = x;
    unsigned r = a.u + 0x7FFF + ((a.u >> 16) & 1);   // round-to-nearest-even
    return (short)(r >> 16);
}
__device__ __forceinline__ float b2f(short s) {
    union { unsigned u; float f; } a; a.u = ((unsigned)(unsigned short)s) << 16;
    return a.f;
}
__device__ __forceinline__ float sigm(float x) { return 1.f / (1.f + __expf(-x)); }

// ---------------- prep ----------------
// wf[0:64]=A(Pin), wf[64:128]=B(Pout), wf[128:192]=C(J)
__global__ __launch_bounds__(64) void prep_wf(const float* __restrict__ W1,
                                              float* __restrict__ wf)
{
    int j = threadIdx.x;
    wf[j]       = W1[64 * 64 + j]  - W1[65 * 64 + j];
    wf[64 + j]  = W1[133 * 64 + j] - W1[132 * 64 + j];
    wf[128 + j] = W1[66 * 64 + j] - W1[67 * 64 + j]
                - W1[134 * 64 + j] + W1[135 * 64 + j];
}

// W2tB[c*64+k] = bf16(W2[k*64+c]); same for W3
__global__ __launch_bounds__(256) void prep_w23(const float* __restrict__ W2,
                                                const float* __restrict__ W3,
                                                short* __restrict__ W2tB,
                                                short* __restrict__ W3tB)
{
    int i = blockIdx.x * 256 + threadIdx.x;
    if (i < 4096) {
        int c = i >> 6, k = i & 63;
        W2tB[i] = f2b(W2[k * 64 + c]);
        W3tB[i] = f2b(W3[k * 64 + c]);
    }
}

__global__ __launch_bounds__(256) void init_state(
    const float* __restrict__ b, const float* __restrict__ W_in,
    const float* __restrict__ b_in,
    float* __restrict__ state, float* __restrict__ agg0, float* __restrict__ agg1)
{
    int idx = blockIdx.x * 256 + threadIdx.x;
    if (idx >= NN * 64) return;
    int n = idx >> 6, j = idx & 63;
    state[idx] = b[n] * (W_in[j] - W_in[64 + j]) + b_in[j];
    agg0[idx] = 0.f;
    agg1[idx] = 0.f;
}

// ---------------- CSR build ----------------
__global__ __launch_bounds__(256) void csr_zero(int* __restrict__ cnt, int* __restrict__ cur)
{
    int i = blockIdx.x * 256 + threadIdx.x;
    if (i < NN) { cnt[i] = 0; cur[i] = 0; }
}

__global__ __launch_bounds__(256) void csr_count(const int* __restrict__ mn, int* __restrict__ cnt)
{
    int e = blockIdx.x * 256 + threadIdx.x;
    if (e < NE) atomicAdd(&cnt[mn[2 * e + 1]], 1);
}

__global__ __launch_bounds__(256) void scan_block(const int* __restrict__ cnt,
                                                  int* __restrict__ base, int* __restrict__ bsum)
{
    __shared__ int s[256];
    int i = blockIdx.x * 256 + threadIdx.x;
    int v = (i < NN) ? cnt[i] : 0;
    s[threadIdx.x] = v;
    __syncthreads();
    for (int off = 1; off < 256; off <<= 1) {
        int t = (threadIdx.x >= off) ? s[threadIdx.x - off] : 0;
        __syncthreads();
        s[threadIdx.x] += t;
        __syncthreads();
    }
    if (i < NN) base[i] = s[threadIdx.x] - v;
    if (threadIdx.x == 255) bsum[blockIdx.x] = s[255];
}

__global__ __launch_bounds__(256) void scan_top(int* __restrict__ bsum, int nb)
{
    __shared__ int s[256];
    int t = threadIdx.x;
    int v = (t < nb) ? bsum[t] : 0;
    s[t] = v;
    __syncthreads();
    for (int off = 1; off < 256; off <<= 1) {
        int u = (t >= off) ? s[t - off] : 0;
        __syncthreads();
        s[t] += u;
        __syncthreads();
    }
    if (t < nb) bsum[t] = s[t] - v;
}

__global__ __launch_bounds__(256) void scan_add(int* __restrict__ base, const int* __restrict__ bsum)
{
    int i = blockIdx.x * 256 + threadIdx.x;
    if (i < NN) base[i] += bsum[blockIdx.x];
}

__global__ __launch_bounds__(256) void csr_scatter_perm(const int* __restrict__ mn,
    const float* __restrict__ Jm,
    const int* __restrict__ base, int* __restrict__ cur,
    int* __restrict__ einP, int* __restrict__ eoutP, float* __restrict__ JP)
{
    int e = blockIdx.x * 256 + threadIdx.x;
    if (e < NE) {
        int n = mn[2 * e + 1];
        int p = base[n] + atomicAdd(&cur[n], 1);
        einP[p]  = mn[2 * e];
        eoutP[p] = n;
        JP[p]    = Jm[e];
    }
}

#define FMA16(xv, wv)                                                        \
    acc[0][0] += xv.x * wv.x; acc[0][1] += xv.x * wv.y;                      \
    acc[0][2] += xv.x * wv.z; acc[0][3] += xv.x * wv.w;                      \
    acc[1][0] += xv.y * wv.x; acc[1][1] += xv.y * wv.y;                      \
    acc[1][2] += xv.y * wv.z; acc[1][3] += xv.y * wv.w;                      \
    acc[2][0] += xv.z * wv.x; acc[2][1] += xv.z * wv.y;                      \
    acc[2][2] += xv.z * wv.z; acc[2][3] += xv.z * wv.w;                      \
    acc[3][0] += xv.w * wv.x; acc[3][1] += xv.w * wv.y;                      \
    acc[3][2] += xv.w * wv.z; acc[3][3] += xv.w * wv.w;

// ---------------- per-node layer-1 projections (fp32) ----------------
__global__ __launch_bounds__(256, 2) void node_proj(
    const float* __restrict__ state, const float* __restrict__ bb,
    const float* __restrict__ W1, const float* __restrict__ wf,
    const float* __restrict__ b1,
    float* __restrict__ Pin, float* __restrict__ Pout)
{
    __shared__ float xh[64][68];
    __shared__ float ws[64][64];
    __shared__ float sb[64];

    int tid = threadIdx.x;
    int ct = blockIdx.x & 1;
    int n0 = (blockIdx.x >> 1) * 64;

    const float* Wbase = W1 + (ct ? 68 * 64 : 0);
    float* P = ct ? Pout : Pin;

    {
        int m = tid & 63, cc = tid >> 6;
        int n = n0 + m;
        bool ok = (n < NN);
#pragma unroll
        for (int r = 0; r < 4; r++) {
            int k = cc * 4 + r * 16;
            float4 v = ok ? *(const float4*)&state[(size_t)n * 64 + k]
                          : make_float4(0.f, 0.f, 0.f, 0.f);
            xh[k + 0][m] = v.x; xh[k + 1][m] = v.y; xh[k + 2][m] = v.z; xh[k + 3][m] = v.w;
        }
        const float4* wsrc = (const float4*)Wbase;
        float4* wdst = (float4*)ws;
#pragma unroll
        for (int r = 0; r < 4; r++) wdst[tid + 256 * r] = wsrc[tid + 256 * r];
        if (tid < 64) sb[tid] = (n0 + tid < NN) ? bb[n0 + tid] : 0.f;
    }
    __syncthreads();

    int tn4 = (tid & 15) * 4, tm4 = (tid >> 4) * 4;
    float acc[4][4];
#pragma unroll
    for (int i = 0; i < 4; i++)
#pragma unroll
        for (int j = 0; j < 4; j++) acc[i][j] = 0.f;

#pragma unroll 8
    for (int k = 0; k < 64; k++) {
        float4 xv = *(const float4*)&xh[k][tm4];
        float4 wv = *(const float4*)&ws[k][tn4];
        FMA16(xv, wv)
    }

    float4 Fv = *(const float4*)&wf[ct * 64 + tn4];
    float4 Bv = ct ? make_float4(0.f, 0.f, 0.f, 0.f) : *(const float4*)&b1[tn4];
    float F[4] = {Fv.x, Fv.y, Fv.z, Fv.w};
    float Bi[4] = {Bv.x, Bv.y, Bv.z, Bv.w};
#pragma unroll
    for (int i = 0; i < 4; i++) {
        int n = n0 + tm4 + i;
        if (n < NN) {
            float bn = sb[tm4 + i];
            float4 v;
            v.x = acc[i][0] + bn * F[0] + Bi[0];
            v.y = acc[i][1] + bn * F[1] + Bi[1];
            v.z = acc[i][2] + bn * F[2] + Bi[2];
            v.w = acc[i][3] + bn * F[3] + Bi[3];
            *(float4*)&P[(size_t)n * 64 + tn4] = v;
        }
    }
}

#define ADD4(A, V) { A.x += V.x; A.y += V.y; A.z += V.z; A.w += V.w; }

// ---------------- edge MLP (layers 2+3) + parallel fused segment-sum ----------------
// 64 CSR-ordered edges x 64 cols; 4 waves. GEMMs as round 5 (split hi+lo MFMA).
// Reduction: segmented Hillis-Steele scan over rows (all 256 threads active),
// ping-pong h1f/h2f scratch; tail rows store (interior: plain, boundary: atomic).
__global__ __launch_bounds__(256, 3) void edge_msg_mfma(
    const int* __restrict__ einP, const int* __restrict__ eoutP,
    const float* __restrict__ JP,
    const float* __restrict__ Pin, const float* __restrict__ Pout,
    const float* __restrict__ wf,
    const short* __restrict__ W2tB, const float* __restrict__ b2,
    const short* __restrict__ W3tB, const float* __restrict__ b3,
    float* __restrict__ agg)
{
    __shared__ float h1f[64][68];
    __shared__ float h2f[64][68];
    __shared__ short w2s[64][72];
    __shared__ short w3s[64][72];
    __shared__ int   seo[64];

    int tid = threadIdx.x;
    int p0 = blockIdx.x * 64;

    // ---- stage ----
    {
        if (tid < 64) seo[tid] = eoutP[p0 + tid];
        int m = tid & 63, kb = (tid >> 6) * 16;
        int a = einP[p0 + m], o = eoutP[p0 + m];
        float J = JP[p0 + m];
#pragma unroll
        for (int q = 0; q < 4; q++) {
            float4 va = *(const float4*)&Pin[(size_t)a * 64 + kb + 4 * q];
            float4 vo = *(const float4*)&Pout[(size_t)o * 64 + kb + 4 * q];
            float4 vc = *(const float4*)&wf[128 + kb + 4 * q];
            float4 r;
            r.x = fmaxf(va.x + vo.x + J * vc.x, 0.f);
            r.y = fmaxf(va.y + vo.y + J * vc.y, 0.f);
            r.z = fmaxf(va.z + vo.z + J * vc.z, 0.f);
            r.w = fmaxf(va.w + vo.w + J * vc.w, 0.f);
            *(float4*)&h1f[m][kb + 4 * q] = r;
        }
        int row = tid >> 2, cb = (tid & 3) * 16;
        *(bh8*)&w2s[row][cb]     = *(const bh8*)&W2tB[row * 64 + cb];
        *(bh8*)&w2s[row][cb + 8] = *(const bh8*)&W2tB[row * 64 + cb + 8];
        *(bh8*)&w3s[row][cb]     = *(const bh8*)&W3tB[row * 64 + cb];
        *(bh8*)&w3s[row][cb + 8] = *(const bh8*)&W3tB[row * 64 + cb + 8];
    }
    __syncthreads();

    int w = tid >> 6, l = tid & 63;
    int lr = l & 15, lg = l >> 4;

    float b2v[4], b3v[4];
#pragma unroll
    for (int ct = 0; ct < 4; ct++) { b2v[ct] = b2[ct * 16 + lr]; b3v[ct] = b3[ct * 16 + lr]; }

    // ---- GEMM2 ----
    {
        float va[8], vb[8];
        *(float4*)&va[0] = *(const float4*)&h1f[16 * w + lr][lg * 8];
        *(float4*)&va[4] = *(const float4*)&h1f[16 * w + lr][lg * 8 + 4];
        *(float4*)&vb[0] = *(const float4*)&h1f[16 * w + lr][lg * 8 + 32];
        *(float4*)&vb[4] = *(const float4*)&h1f[16 * w + lr][lg * 8 + 36];
        bh8 Ahi1, Alo1, Ahi2, Alo2;
#pragma unroll
        for (int j = 0; j < 8; j++) {
            short h = f2b(va[j]); Ahi1[j] = h; Alo1[j] = f2b(va[j] - b2f(h));
            short g = f2b(vb[j]); Ahi2[j] = g; Alo2[j] = f2b(vb[j] - b2f(g));
        }
#pragma unroll
        for (int ct = 0; ct < 4; ct++) {
            bh8 B1 = *(const bh8*)&w2s[16 * ct + lr][lg * 8];
            bh8 B2 = *(const bh8*)&w2s[16 * ct + lr][lg * 8 + 32];
            fx4 acc = {0.f, 0.f, 0.f, 0.f};
            acc = __builtin_amdgcn_mfma_f32_16x16x32_bf16(Ahi1, B1, acc, 0, 0, 0);
            acc = __builtin_amdgcn_mfma_f32_16x16x32_bf16(Alo1, B1, acc, 0, 0, 0);
            acc = __builtin_amdgcn_mfma_f32_16x16x32_bf16(Ahi2, B2, acc, 0, 0, 0);
            acc = __builtin_amdgcn_mfma_f32_16x16x32_bf16(Alo2, B2, acc, 0, 0, 0);
#pragma unroll
            for (int r = 0; r < 4; r++)
                h2f[16 * w + 4 * lg + r][16 * ct + lr] = fmaxf(acc[r] + b2v[ct], 0.f);
        }
    }

    // ---- GEMM3 (band-private through LDS) ----
    {
        float va[8], vb[8];
        *(float4*)&va[0] = *(const float4*)&h2f[16 * w + lr][lg * 8];
        *(float4*)&va[4] = *(const float4*)&h2f[16 * w + lr][lg * 8 + 4];
        *(float4*)&vb[0] = *(const float4*)&h2f[16 * w + lr][lg * 8 + 32];
        *(float4*)&vb[4] = *(const float4*)&h2f[16 * w + lr][lg * 8 + 36];
        bh8 Chi1, Clo1, Chi2, Clo2;
#pragma unroll
        for (int j = 0; j < 8; j++) {
            short h = f2b(va[j]); Chi1[j] = h; Clo1[j] = f2b(va[j] - b2f(h));
            short g = f2b(vb[j]); Chi2[j] = g; Clo2[j] = f2b(vb[j] - b2f(g));
        }
#pragma unroll
        for (int ct = 0; ct < 4; ct++) {
            bh8 B1 = *(const bh8*)&w3s[16 * ct + lr][lg * 8];
            bh8 B2 = *(const bh8*)&w3s[16 * ct + lr][lg * 8 + 32];
            fx4 acc = {0.f, 0.f, 0.f, 0.f};
            acc = __builtin_amdgcn_mfma_f32_16x16x32_bf16(Chi1, B1, acc, 0, 0, 0);
            acc = __builtin_amdgcn_mfma_f32_16x16x32_bf16(Clo1, B1, acc, 0, 0, 0);
            acc = __builtin_amdgcn_mfma_f32_16x16x32_bf16(Chi2, B2, acc, 0, 0, 0);
            acc = __builtin_amdgcn_mfma_f32_16x16x32_bf16(Clo2, B2, acc, 0, 0, 0);
#pragma unroll
            for (int r = 0; r < 4; r++)
                h1f[16 * w + 4 * lg + r][16 * ct + lr] = acc[r] + b3v[ct];   // m -> own band
        }
    }

    __syncthreads();   // all m values visible in h1f

    // ---- segmented scan over rows (prefix per (row, col-quarter)) ----
    {
        int r  = tid >> 2;
        int c4 = (tid & 3) << 4;
        int n  = seo[r];
        float4 a0 = *(const float4*)&h1f[r][c4];
        float4 a1 = *(const float4*)&h1f[r][c4 + 4];
        float4 a2 = *(const float4*)&h1f[r][c4 + 8];
        float4 a3 = *(const float4*)&h1f[r][c4 + 12];

        // off=1: read initial values still in h1f
        if (r >= 1 && seo[r - 1] == n) {
            float4 v0 = *(const float4*)&h1f[r - 1][c4];
            float4 v1 = *(const float4*)&h1f[r - 1][c4 + 4];
            float4 v2 = *(const float4*)&h1f[r - 1][c4 + 8];
            float4 v3 = *(const float4*)&h1f[r - 1][c4 + 12];
            ADD4(a0, v0) ADD4(a1, v1) ADD4(a2, v2) ADD4(a3, v3)
        }
        // off = 2,4,8,16,32 : write prefix, barrier, read r-off
#pragma unroll
        for (int s = 1; s <= 5; s++) {
            int off = 1 << s;
            float (*buf)[68] = (s & 1) ? h2f : h1f;   // s=1->h2f, s=2->h1f, ...
            *(float4*)&buf[r][c4]      = a0;
            *(float4*)&buf[r][c4 + 4]  = a1;
            *(float4*)&buf[r][c4 + 8]  = a2;
            *(float4*)&buf[r][c4 + 12] = a3;
            __syncthreads();
            if (r >= off && seo[r - off] == n) {
                float4 v0 = *(const float4*)&buf[r - off][c4];
                float4 v1 = *(const float4*)&buf[r - off][c4 + 4];
                float4 v2 = *(const float4*)&buf[r - off][c4 + 8];
                float4 v3 = *(const float4*)&buf[r - off][c4 + 12];
                ADD4(a0, v0) ADD4(a1, v1) ADD4(a2, v2) ADD4(a3, v3)
            }
            __syncthreads();   // reads done before next step's writes
        }

        bool tail = (r == 63) || (seo[r + 1] != n);
        if (tail) {
            float* ar = agg + (size_t)n * 64 + c4;
            bool interior = (r < 63) && (seo[0] != n);
            if (interior) {
                *(float4*)&ar[0]  = a0;
                *(float4*)&ar[4]  = a1;
                *(float4*)&ar[8]  = a2;
                *(float4*)&ar[12] = a3;
            } else {
                atomicAdd(ar + 0,  a0.x); atomicAdd(ar + 1,  a0.y);
                atomicAdd(ar + 2,  a0.z); atomicAdd(ar + 3,  a0.w);
                atomicAdd(ar + 4,  a1.x); atomicAdd(ar + 5,  a1.y);
                atomicAdd(ar + 6,  a1.z); atomicAdd(ar + 7,  a1.w);
                atomicAdd(ar + 8,  a2.x); atomicAdd(ar + 9,  a2.y);
                atomicAdd(ar + 10, a2.z); atomicAdd(ar + 11, a2.w);
                atomicAdd(ar + 12, a3.x); atomicAdd(ar + 13, a3.y);
                atomicAdd(ar + 14, a3.z); atomicAdd(ar + 15, a3.w);
            }
        }
    }
}

// ---------------- fused GRU: gi/gh GEMMs + gates + state write ----------------
// Block = (64-node tile) x (16 gate-columns). Thread: 4 nodes x 1 col x {r,z,n}x{i,h}.
// Writes stateNext (ping-pong; no reader conflict), zeroes aggNext quarter.
__global__ __launch_bounds__(256, 2) void gru_fused(
    const float* __restrict__ agg, const float* __restrict__ state,
    const float* __restrict__ Wih, const float* __restrict__ Whh,
    const float* __restrict__ bih, const float* __restrict__ bhh,
    float* __restrict__ stateNext, float* __restrict__ aggNext)
{
    __shared__ float xa[64][68];    // agg, K-major [k][m]
    __shared__ float xh[64][68];    // state, K-major [k][m]
    __shared__ float wiS[64][48];   // Wih[k][{r,z,n} x 16 cols]
    __shared__ float whS[64][48];

    int tid = threadIdx.x;
    int tile = blockIdx.x >> 2, q = blockIdx.x & 3;
    int n0 = tile * 64;

    {
        int m = tid & 63, c = tid >> 6;
        int n = n0 + m;
        bool ok = (n < NN);
#pragma unroll
        for (int r = 0; r < 4; r++) {
            int k = c * 4 + r * 16;
            float4 v = ok ? *(const float4*)&agg[(size_t)n * 64 + k]
                          : make_float4(0.f, 0.f, 0.f, 0.f);
            xa[k + 0][m] = v.x; xa[k + 1][m] = v.y; xa[k + 2][m] = v.z; xa[k + 3][m] = v.w;
            float4 u = ok ? *(const float4*)&state[(size_t)n * 64 + k]
                          : make_float4(0.f, 0.f, 0.f, 0.f);
            xh[k + 0][m] = u.x; xh[k + 1][m] = u.y; xh[k + 2][m] = u.z; xh[k + 3][m] = u.w;
        }
        // weights: 64k x 48 cols = 3072 = 12*256
#pragma unroll
        for (int r = 0; r < 12; r++) {
            int flat = r * 256 + tid;
            int k = flat / 48, col = flat % 48;
            int g = col >> 4, ci = col & 15;
            wiS[k][col] = Wih[(size_t)k * 192 + g * 64 + q * 16 + ci];
            whS[k][col] = Whh[(size_t)k * 192 + g * 64 + q * 16 + ci];
        }
    }
    __syncthreads();

    int ci = tid & 15, m4 = (tid >> 4) * 4;
    float gir[4] = {0,0,0,0}, giz[4] = {0,0,0,0}, gin[4] = {0,0,0,0};
    float ghr[4] = {0,0,0,0}, ghz[4] = {0,0,0,0}, ghn[4] = {0,0,0,0};

#pragma unroll 4
    for (int k = 0; k < 64; k++) {
        float4 xv = *(const float4*)&xa[k][m4];
        float4 hv = *(const float4*)&xh[k][m4];
        float wir = wiS[k][ci], wiz = wiS[k][16 + ci], win = wiS[k][32 + ci];
        float whr = whS[k][ci], whz = whS[k][16 + ci], whn = whS[k][32 + ci];
        gir[0] += xv.x * wir; gir[1] += xv.y * wir; gir[2] += xv.z * wir; gir[3] += xv.w * wir;
        giz[0] += xv.x * wiz; giz[1] += xv.y * wiz; giz[2] += xv.z * wiz; giz[3] += xv.w * wiz;
        gin[0] += xv.x * win; gin[1] += xv.y * win; gin[2] += xv.z * win; gin[3] += xv.w * win;
        ghr[0] += hv.x * whr; ghr[1] += hv.y * whr; ghr[2] += hv.z * whr; ghr[3] += hv.w * whr;
        ghz[0] += hv.x * whz; ghz[1] += hv.y * whz; ghz[2] += hv.z * whz; ghz[3] += hv.w * whz;
        ghn[0] += hv.x * whn; ghn[1] += hv.y * whn; ghn[2] += hv.z * whn; ghn[3] += hv.w * whn;
    }

    int c = q * 16 + ci;
    float bir = bih[c], biz = bih[64 + c], bin = bih[128 + c];
    float bhr = bhh[c], bhz = bhh[64 + c], bhn = bhh[128 + c];
#pragma unroll
    for (int i = 0; i < 4; i++) {
        int n = n0 + m4 + i;
        if (n < NN) {
            float hold = xh[c][m4 + i];
            float r = sigm(gir[i] + bir + ghr[i] + bhr);
            float z = sigm(giz[i] + biz + ghz[i] + bhz);
            float ng = tanhf(gin[i] + bin + r * (ghn[i] + bhn));
            stateNext[(size_t)n * 64 + c] = (1.f - z) * ng + z * hold;
            aggNext[(size_t)n * 64 + c] = 0.f;
        }
    }
}

__global__ __launch_bounds__(256) void out_proj(
    const float* __restrict__ state, const float* __restrict__ Wout,
    const float* __restrict__ bout, float* __restrict__ out)
{
    int n = blockIdx.x * 256 + threadIdx.x;
    if (n >= NN) return;
    float a0 = bout[0], a1 = bout[1];
    const float4* sr = (const float4*)(state + (size_t)n * 64);
#pragma unroll
    for (int t = 0; t < 16; t++) {
        float4 v = sr[t];
        a0 += v.x * Wout[2 * (4 * t + 0)] + v.y * Wout[2 * (4 * t + 1)]
            + v.z * Wout[2 * (4 * t + 2)] + v.w * Wout[2 * (4 * t + 3)];
        a1 += v.x * Wout[2 * (4 * t + 0) + 1] + v.y * Wout[2 * (4 * t + 1) + 1]
            + v.z * Wout[2 * (4 * t + 2) + 1] + v.w * Wout[2 * (4 * t + 3) + 1];
    }
    out[2 * n] = a0;
    out[2 * n + 1] = a1;
}

extern "C" void kernel_launch(void* const* d_in, const int* in_sizes, int n_in,
                              void* d_out, int out_size, void* d_ws, size_t ws_size,
                              hipStream_t stream)
{
    const int*   msg_node = (const int*)  d_in[0];
    const float* J_msg    = (const float*)d_in[1];
    const float* b        = (const float*)d_in[2];
    const float* W_in     = (const float*)d_in[4];
    const float* b_in     = (const float*)d_in[5];
    const float* W1       = (const float*)d_in[6];
    const float* b1       = (const float*)d_in[7];
    const float* W2       = (const float*)d_in[8];
    const float* b2       = (const float*)d_in[9];
    const float* W3       = (const float*)d_in[10];
    const float* b3       = (const float*)d_in[11];
    const float* W_ih     = (const float*)d_in[12];
    const float* b_ih     = (const float*)d_in[13];
    const float* W_hh     = (const float*)d_in[14];
    const float* b_hh     = (const float*)d_in[15];
    const float* W_out    = (const float*)d_in[16];
    const float* b_out    = (const float*)d_in[17];

    float* f      = (float*)d_ws;
    float* state0 = f;                                  // NN*64
    float* state1 = state0 + (size_t)NN * 64;           // NN*64
    float* agg0   = state1 + (size_t)NN * 64;           // NN*64
    float* agg1   = agg0   + (size_t)NN * 64;           // NN*64
    float* Pin    = agg1   + (size_t)NN * 64;           // NN*64
    float* Pout   = Pin    + (size_t)NN * 64;           // NN*64
    float* wf     = Pout   + (size_t)NN * 64;           // 192
    float* JP     = wf + 192;                           // NE
    int*   einP   = (int*)(JP + NE);                    // NE
    int*   eoutP  = einP + NE;                          // NE
    int*   cbase  = eoutP + NE;                         // NN
    int*   ccnt   = cbase + NN;                         // NN
    int*   ccur   = ccnt + NN;                          // NN
    int*   cbsum  = ccur + NN;                          // 512
    short* W2tB   = (short*)(cbsum + 512);              // 4096 bf16
    short* W3tB   = W2tB + 4096;                        // 4096 bf16

    float* stateBuf[2] = { state0, state1 };
    float* aggBuf[2]   = { agg0, agg1 };
    float* out = (float*)d_out;

    prep_wf<<<1, 64, 0, stream>>>(W1, wf);
    prep_w23<<<16, 256, 0, stream>>>(W2, W3, W2tB, W3tB);
    init_state<<<(NN * 64 + 255) / 256, 256, 0, stream>>>(b, W_in, b_in,
                                                          state0, agg0, agg1);

    csr_zero<<<(NN + 255) / 256, 256, 0, stream>>>(ccnt, ccur);
    csr_count<<<(NE + 255) / 256, 256, 0, stream>>>(msg_node, ccnt);
    scan_block<<<(NN + 255) / 256, 256, 0, stream>>>(ccnt, cbase, cbsum);
    scan_top<<<1, 256, 0, stream>>>(cbsum, (NN + 255) / 256);
    scan_add<<<(NN + 255) / 256, 256, 0, stream>>>(cbase, cbsum);
    csr_scatter_perm<<<(NE + 255) / 256, 256, 0, stream>>>(msg_node, J_msg, cbase, ccur,
                                                           einP, eoutP, JP);

    int ntile = (NN + 63) / 64;
    for (int p = 0; p < 3; p++) {
        float* sc = stateBuf[p & 1];
        float* sn = stateBuf[(p + 1) & 1];
        float* ac = aggBuf[p & 1];
        float* an = aggBuf[(p + 1) & 1];
        node_proj<<<ntile * 2, 256, 0, stream>>>(sc, b, W1, wf, b1, Pin, Pout);
        edge_msg_mfma<<<NE / 64, 256, 0, stream>>>(einP, eoutP, JP, Pin, Pout, wf,
                                                   W2tB, b2, W3tB, b3, ac);
        gru_fused<<<ntile * 4, 256, 0, stream>>>(ac, sc, W_ih, W_hh, b_ih, b_hh,
                                                 sn, an);
    }
    out_proj<<<(NN + 255) / 256, 256, 0, stream>>>(stateBuf[1], W_out, b_out, out);
}

// Round 8
// 565.706 us; speedup vs baseline: 1.6627x; 1.6291x over previous
//
#include <hip/hip_runtime.h>
#include <math.h>

#define NN 50000
#define NE 800000

typedef __attribute__((ext_vector_type(8))) short bh8;   // 8 bf16 = 4 VGPR (MFMA A/B frag)
typedef __attribute__((ext_vector_type(4))) float fx4;   // MFMA C/D frag

__device__ __forceinline__ short f2b(float x) {
    union { float f; unsigned u; } a; a.f = x;
    unsigned r = a.u + 0x7FFF + ((a.u >> 16) & 1);   // round-to-nearest-even
    return (short)(r >> 16);
}
__device__ __forceinline__ float b2f(short s) {
    union { unsigned u; float f; } a; a.u = ((unsigned)(unsigned short)s) << 16;
    return a.f;
}
__device__ __forceinline__ float sigm(float x) { return 1.f / (1.f + __expf(-x)); }

// ---------------- prep ----------------
// wf[0:64]=A(Pin), wf[64:128]=B(Pout), wf[128:192]=C(J)
__global__ __launch_bounds__(64) void prep_wf(const float* __restrict__ W1,
                                              float* __restrict__ wf)
{
    int j = threadIdx.x;
    wf[j]       = W1[64 * 64 + j]  - W1[65 * 64 + j];
    wf[64 + j]  = W1[133 * 64 + j] - W1[132 * 64 + j];
    wf[128 + j] = W1[66 * 64 + j] - W1[67 * 64 + j]
                - W1[134 * 64 + j] + W1[135 * 64 + j];
}

// W2tB[c*64+k] = bf16(W2[k*64+c]); same for W3
__global__ __launch_bounds__(256) void prep_w23(const float* __restrict__ W2,
                                                const float* __restrict__ W3,
                                                short* __restrict__ W2tB,
                                                short* __restrict__ W3tB)
{
    int i = blockIdx.x * 256 + threadIdx.x;
    if (i < 4096) {
        int c = i >> 6, k = i & 63;
        W2tB[i] = f2b(W2[k * 64 + c]);
        W3tB[i] = f2b(W3[k * 64 + c]);
    }
}

__global__ __launch_bounds__(256) void init_state(
    const float* __restrict__ b, const float* __restrict__ W_in,
    const float* __restrict__ b_in,
    float* __restrict__ state, float* __restrict__ agg0, float* __restrict__ agg1)
{
    int idx = blockIdx.x * 256 + threadIdx.x;
    if (idx >= NN * 64) return;
    int n = idx >> 6, j = idx & 63;
    state[idx] = b[n] * (W_in[j] - W_in[64 + j]) + b_in[j];
    agg0[idx] = 0.f;
    agg1[idx] = 0.f;
}

// ---------------- CSR build ----------------
__global__ __launch_bounds__(256) void csr_zero(int* __restrict__ cnt, int* __restrict__ cur)
{
    int i = blockIdx.x * 256 + threadIdx.x;
    if (i < NN) { cnt[i] = 0; cur[i] = 0; }
}

__global__ __launch_bounds__(256) void csr_count(const int* __restrict__ mn, int* __restrict__ cnt)
{
    int e = blockIdx.x * 256 + threadIdx.x;
    if (e < NE) atomicAdd(&cnt[mn[2 * e + 1]], 1);
}

__global__ __launch_bounds__(256) void scan_block(const int* __restrict__ cnt,
                                                  int* __restrict__ base, int* __restrict__ bsum)
{
    __shared__ int s[256];
    int i = blockIdx.x * 256 + threadIdx.x;
    int v = (i < NN) ? cnt[i] : 0;
    s[threadIdx.x] = v;
    __syncthreads();
    for (int off = 1; off < 256; off <<= 1) {
        int t = (threadIdx.x >= off) ? s[threadIdx.x - off] : 0;
        __syncthreads();
        s[threadIdx.x] += t;
        __syncthreads();
    }
    if (i < NN) base[i] = s[threadIdx.x] - v;
    if (threadIdx.x == 255) bsum[blockIdx.x] = s[255];
}

__global__ __launch_bounds__(256) void scan_top(int* __restrict__ bsum, int nb)
{
    __shared__ int s[256];
    int t = threadIdx.x;
    int v = (t < nb) ? bsum[t] : 0;
    s[t] = v;
    __syncthreads();
    for (int off = 1; off < 256; off <<= 1) {
        int u = (t >= off) ? s[t - off] : 0;
        __syncthreads();
        s[t] += u;
        __syncthreads();
    }
    if (t < nb) bsum[t] = s[t] - v;
}

__global__ __launch_bounds__(256) void scan_add(int* __restrict__ base, const int* __restrict__ bsum)
{
    int i = blockIdx.x * 256 + threadIdx.x;
    if (i < NN) base[i] += bsum[blockIdx.x];
}

__global__ __launch_bounds__(256) void csr_scatter_perm(const int* __restrict__ mn,
    const float* __restrict__ Jm,
    const int* __restrict__ base, int* __restrict__ cur,
    int* __restrict__ einP, int* __restrict__ eoutP, float* __restrict__ JP)
{
    int e = blockIdx.x * 256 + threadIdx.x;
    if (e < NE) {
        int n = mn[2 * e + 1];
        int p = base[n] + atomicAdd(&cur[n], 1);
        einP[p]  = mn[2 * e];
        eoutP[p] = n;
        JP[p]    = Jm[e];
    }
}

#define FMA16(xv, wv)                                                        \
    acc[0][0] += xv.x * wv.x; acc[0][1] += xv.x * wv.y;                      \
    acc[0][2] += xv.x * wv.z; acc[0][3] += xv.x * wv.w;                      \
    acc[1][0] += xv.y * wv.x; acc[1][1] += xv.y * wv.y;                      \
    acc[1][2] += xv.y * wv.z; acc[1][3] += xv.y * wv.w;                      \
    acc[2][0] += xv.z * wv.x; acc[2][1] += xv.z * wv.y;                      \
    acc[2][2] += xv.z * wv.z; acc[2][3] += xv.z * wv.w;                      \
    acc[3][0] += xv.w * wv.x; acc[3][1] += xv.w * wv.y;                      \
    acc[3][2] += xv.w * wv.z; acc[3][3] += xv.w * wv.w;

// ---------------- per-node layer-1 projections (fp32) ----------------
__global__ __launch_bounds__(256, 2) void node_proj(
    const float* __restrict__ state, const float* __restrict__ bb,
    const float* __restrict__ W1, const float* __restrict__ wf,
    const float* __restrict__ b1,
    float* __restrict__ Pin, float* __restrict__ Pout)
{
    __shared__ float xh[64][68];
    __shared__ float ws[64][64];
    __shared__ float sb[64];

    int tid = threadIdx.x;
    int ct = blockIdx.x & 1;
    int n0 = (blockIdx.x >> 1) * 64;

    const float* Wbase = W1 + (ct ? 68 * 64 : 0);
    float* P = ct ? Pout : Pin;

    {
        int m = tid & 63, cc = tid >> 6;
        int n = n0 + m;
        bool ok = (n < NN);
#pragma unroll
        for (int r = 0; r < 4; r++) {
            int k = cc * 4 + r * 16;
            float4 v = ok ? *(const float4*)&state[(size_t)n * 64 + k]
                          : make_float4(0.f, 0.f, 0.f, 0.f);
            xh[k + 0][m] = v.x; xh[k + 1][m] = v.y; xh[k + 2][m] = v.z; xh[k + 3][m] = v.w;
        }
        const float4* wsrc = (const float4*)Wbase;
        float4* wdst = (float4*)ws;
#pragma unroll
        for (int r = 0; r < 4; r++) wdst[tid + 256 * r] = wsrc[tid + 256 * r];
        if (tid < 64) sb[tid] = (n0 + tid < NN) ? bb[n0 + tid] : 0.f;
    }
    __syncthreads();

    int tn4 = (tid & 15) * 4, tm4 = (tid >> 4) * 4;
    float acc[4][4];
#pragma unroll
    for (int i = 0; i < 4; i++)
#pragma unroll
        for (int j = 0; j < 4; j++) acc[i][j] = 0.f;

#pragma unroll 8
    for (int k = 0; k < 64; k++) {
        float4 xv = *(const float4*)&xh[k][tm4];
        float4 wv = *(const float4*)&ws[k][tn4];
        FMA16(xv, wv)
    }

    float4 Fv = *(const float4*)&wf[ct * 64 + tn4];
    float4 Bv = ct ? make_float4(0.f, 0.f, 0.f, 0.f) : *(const float4*)&b1[tn4];
    float F[4] = {Fv.x, Fv.y, Fv.z, Fv.w};
    float Bi[4] = {Bv.x, Bv.y, Bv.z, Bv.w};
#pragma unroll
    for (int i = 0; i < 4; i++) {
        int n = n0 + tm4 + i;
        if (n < NN) {
            float bn = sb[tm4 + i];
            float4 v;
            v.x = acc[i][0] + bn * F[0] + Bi[0];
            v.y = acc[i][1] + bn * F[1] + Bi[1];
            v.z = acc[i][2] + bn * F[2] + Bi[2];
            v.w = acc[i][3] + bn * F[3] + Bi[3];
            *(float4*)&P[(size_t)n * 64 + tn4] = v;
        }
    }
}

// ---------------- edge MLP (layers 2+3) + register-level fused segment-sum ----------------
// 64 CSR-ordered edges x 64 cols; 4 waves, wave w owns band [16w,16w+16).
// GEMM3 output stays in regs (C/D frag: row=16w+4*lg+r, col=16ct+lr).
// Segmented scan: in-lane (3 adds) -> cross-chunk via 12 __shfl -> cross-band
// via tband LDS + ONE barrier. Tails: interior runs plain store, boundary atomic.
__global__ __launch_bounds__(256, 3) void edge_msg_mfma(
    const int* __restrict__ einP, const int* __restrict__ eoutP,
    const float* __restrict__ JP,
    const float* __restrict__ Pin, const float* __restrict__ Pout,
    const float* __restrict__ wf,
    const short* __restrict__ W2tB, const float* __restrict__ b2,
    const short* __restrict__ W3tB, const float* __restrict__ b3,
    float* __restrict__ agg)
{
    __shared__ float h1f[64][68];   // h1, then overwritten by h2 (within-wave in-order ds ops)
    __shared__ short w2s[64][72];
    __shared__ short w3s[64][72];
    __shared__ int   seo[64];
    __shared__ float tband[4][64];  // per-band trailing-run partial sums

    int tid = threadIdx.x;
    int p0 = blockIdx.x * 64;

    // ---- stage ----
    {
        if (tid < 64) seo[tid] = eoutP[p0 + tid];
        int m = tid & 63, kb = (tid >> 6) * 16;
        int a = einP[p0 + m], o = eoutP[p0 + m];
        float J = JP[p0 + m];
#pragma unroll
        for (int q = 0; q < 4; q++) {
            float4 va = *(const float4*)&Pin[(size_t)a * 64 + kb + 4 * q];
            float4 vo = *(const float4*)&Pout[(size_t)o * 64 + kb + 4 * q];
            float4 vc = *(const float4*)&wf[128 + kb + 4 * q];
            float4 r;
            r.x = fmaxf(va.x + vo.x + J * vc.x, 0.f);
            r.y = fmaxf(va.y + vo.y + J * vc.y, 0.f);
            r.z = fmaxf(va.z + vo.z + J * vc.z, 0.f);
            r.w = fmaxf(va.w + vo.w + J * vc.w, 0.f);
            *(float4*)&h1f[m][kb + 4 * q] = r;
        }
        int row = tid >> 2, cb = (tid & 3) * 16;
        *(bh8*)&w2s[row][cb]     = *(const bh8*)&W2tB[row * 64 + cb];
        *(bh8*)&w2s[row][cb + 8] = *(const bh8*)&W2tB[row * 64 + cb + 8];
        *(bh8*)&w3s[row][cb]     = *(const bh8*)&W3tB[row * 64 + cb];
        *(bh8*)&w3s[row][cb + 8] = *(const bh8*)&W3tB[row * 64 + cb + 8];
    }
    __syncthreads();

    int w = tid >> 6, l = tid & 63;
    int lr = l & 15, lg = l >> 4;

    float b2v[4], b3v[4];
#pragma unroll
    for (int ct = 0; ct < 4; ct++) { b2v[ct] = b2[ct * 16 + lr]; b3v[ct] = b3[ct * 16 + lr]; }

    // ---- GEMM2: h2 = relu(h1 @ W2 + b2); h2 overwrites h1f (own band, same wave) ----
    {
        float va[8], vb[8];
        *(float4*)&va[0] = *(const float4*)&h1f[16 * w + lr][lg * 8];
        *(float4*)&va[4] = *(const float4*)&h1f[16 * w + lr][lg * 8 + 4];
        *(float4*)&vb[0] = *(const float4*)&h1f[16 * w + lr][lg * 8 + 32];
        *(float4*)&vb[4] = *(const float4*)&h1f[16 * w + lr][lg * 8 + 36];
        bh8 Ahi1, Alo1, Ahi2, Alo2;
#pragma unroll
        for (int j = 0; j < 8; j++) {
            short h = f2b(va[j]); Ahi1[j] = h; Alo1[j] = f2b(va[j] - b2f(h));
            short g = f2b(vb[j]); Ahi2[j] = g; Alo2[j] = f2b(vb[j] - b2f(g));
        }
#pragma unroll
        for (int ct = 0; ct < 4; ct++) {
            bh8 B1 = *(const bh8*)&w2s[16 * ct + lr][lg * 8];
            bh8 B2 = *(const bh8*)&w2s[16 * ct + lr][lg * 8 + 32];
            fx4 acc = {0.f, 0.f, 0.f, 0.f};
            acc = __builtin_amdgcn_mfma_f32_16x16x32_bf16(Ahi1, B1, acc, 0, 0, 0);
            acc = __builtin_amdgcn_mfma_f32_16x16x32_bf16(Alo1, B1, acc, 0, 0, 0);
            acc = __builtin_amdgcn_mfma_f32_16x16x32_bf16(Ahi2, B2, acc, 0, 0, 0);
            acc = __builtin_amdgcn_mfma_f32_16x16x32_bf16(Alo2, B2, acc, 0, 0, 0);
#pragma unroll
            for (int r = 0; r < 4; r++)
                h1f[16 * w + 4 * lg + r][16 * ct + lr] = fmaxf(acc[r] + b2v[ct], 0.f);
        }
    }

    // ---- GEMM3: m = h2 @ W3 + b3 -> registers ----
    fx4 macc[4];
    {
        float va[8], vb[8];
        *(float4*)&va[0] = *(const float4*)&h1f[16 * w + lr][lg * 8];
        *(float4*)&va[4] = *(const float4*)&h1f[16 * w + lr][lg * 8 + 4];
        *(float4*)&vb[0] = *(const float4*)&h1f[16 * w + lr][lg * 8 + 32];
        *(float4*)&vb[4] = *(const float4*)&h1f[16 * w + lr][lg * 8 + 36];
        bh8 Chi1, Clo1, Chi2, Clo2;
#pragma unroll
        for (int j = 0; j < 8; j++) {
            short h = f2b(va[j]); Chi1[j] = h; Clo1[j] = f2b(va[j] - b2f(h));
            short g = f2b(vb[j]); Chi2[j] = g; Clo2[j] = f2b(vb[j] - b2f(g));
        }
#pragma unroll
        for (int ct = 0; ct < 4; ct++) {
            bh8 B1 = *(const bh8*)&w3s[16 * ct + lr][lg * 8];
            bh8 B2 = *(const bh8*)&w3s[16 * ct + lr][lg * 8 + 32];
            fx4 acc = {0.f, 0.f, 0.f, 0.f};
            acc = __builtin_amdgcn_mfma_f32_16x16x32_bf16(Chi1, B1, acc, 0, 0, 0);
            acc = __builtin_amdgcn_mfma_f32_16x16x32_bf16(Clo1, B1, acc, 0, 0, 0);
            acc = __builtin_amdgcn_mfma_f32_16x16x32_bf16(Chi2, B2, acc, 0, 0, 0);
            acc = __builtin_amdgcn_mfma_f32_16x16x32_bf16(Clo2, B2, acc, 0, 0, 0);
#pragma unroll
            for (int r = 0; r < 4; r++) acc[r] += b3v[ct];
            macc[ct] = acc;
        }
    }

    // ---- segmented scan, in registers ----
    int rowb = 16 * w + 4 * lg;
    int s0 = seo[rowb], s1 = seo[rowb + 1], s2 = seo[rowb + 2], s3 = seo[rowb + 3];

    // phase 1: in-lane (rows 4lg..4lg+3)
#pragma unroll
    for (int ct = 0; ct < 4; ct++) {
        if (s1 == s0) macc[ct][1] += macc[ct][0];
        if (s2 == s1) macc[ct][2] += macc[ct][1];
        if (s3 == s2) macc[ct][3] += macc[ct][2];
    }

    // phase 2: cross-chunk (lg) carries via shuffles (read pre-update trailing values)
    float c0[4], c1[4], c2[4];
#pragma unroll
    for (int ct = 0; ct < 4; ct++) {
        c0[ct] = __shfl(macc[ct][3], lr, 64);
        c1[ct] = __shfl(macc[ct][3], lr + 16, 64);
        c2[ct] = __shfl(macc[ct][3], lr + 32, 64);
    }
    {
        int k0 = seo[16 * w + 3], k1 = seo[16 * w + 7], k2 = seo[16 * w + 11];
        float cy[4] = {0.f, 0.f, 0.f, 0.f};
        bool m0 = (lg >= 1) && (k0 == s0);
        bool m1 = (lg >= 2) && (k1 == s0);
        bool m2 = (lg >= 3) && (k2 == s0);
#pragma unroll
        for (int ct = 0; ct < 4; ct++) {
            if (m0) cy[ct] += c0[ct];
            if (m1) cy[ct] += c1[ct];
            if (m2) cy[ct] += c2[ct];
        }
#pragma unroll
        for (int ct = 0; ct < 4; ct++) {
            macc[ct][0] += cy[ct];                 // row 0 of chunk always in leading run
            if (s1 == s0) macc[ct][1] += cy[ct];
            if (s2 == s0) macc[ct][2] += cy[ct];
            if (s3 == s0) macc[ct][3] += cy[ct];
        }
    }

    // phase 3: cross-band via tband (one barrier)
    if (lg == 3) {
#pragma unroll
        for (int ct = 0; ct < 4; ct++) tband[w][16 * ct + lr] = macc[ct][3];
    }
    __syncthreads();
    {
        int bkey = seo[16 * w];
        int t0 = seo[15], t1 = seo[31], t2 = seo[47];
        float bc[4] = {0.f, 0.f, 0.f, 0.f};
        bool m0 = (w >= 1) && (t0 == bkey);
        bool m1 = (w >= 2) && (t1 == bkey);
        bool m2 = (w >= 3) && (t2 == bkey);
#pragma unroll
        for (int ct = 0; ct < 4; ct++) {
            if (m0) bc[ct] += tband[0][16 * ct + lr];
            if (m1) bc[ct] += tband[1][16 * ct + lr];
            if (m2) bc[ct] += tband[2][16 * ct + lr];
        }
#pragma unroll
        for (int ct = 0; ct < 4; ct++) {
            if (s0 == bkey) macc[ct][0] += bc[ct];
            if (s1 == bkey) macc[ct][1] += bc[ct];
            if (s2 == bkey) macc[ct][2] += bc[ct];
            if (s3 == bkey) macc[ct][3] += bc[ct];
        }
    }

    // ---- emit tails ----
    {
        int nh = seo[0], nt = seo[63];
        int sr[4] = { s0, s1, s2, s3 };
#pragma unroll
        for (int r = 0; r < 4; r++) {
            int p = rowb + r;
            int n = sr[r];
            bool tail = (p == 63) || (seo[p + 1] != n);
            if (tail) {
                float* ar = agg + (size_t)n * 64;
                if (n != nh && n != nt) {
                    ar[lr]      = macc[0][r];
                    ar[16 + lr] = macc[1][r];
                    ar[32 + lr] = macc[2][r];
                    ar[48 + lr] = macc[3][r];
                } else {
                    atomicAdd(&ar[lr],      macc[0][r]);
                    atomicAdd(&ar[16 + lr], macc[1][r]);
                    atomicAdd(&ar[32 + lr], macc[2][r]);
                    atomicAdd(&ar[48 + lr], macc[3][r]);
                }
            }
        }
    }
}

// ---------------- fused GRU: gi/gh GEMMs + gates + state write ----------------
__global__ __launch_bounds__(256, 2) void gru_fused(
    const float* __restrict__ agg, const float* __restrict__ state,
    const float* __restrict__ Wih, const float* __restrict__ Whh,
    const float* __restrict__ bih, const float* __restrict__ bhh,
    float* __restrict__ stateNext, float* __restrict__ aggNext)
{
    __shared__ float xa[64][68];
    __shared__ float xh[64][68];
    __shared__ float wiS[64][48];
    __shared__ float whS[64][48];

    int tid = threadIdx.x;
    int tile = blockIdx.x >> 2, q = blockIdx.x & 3;
    int n0 = tile * 64;

    {
        int m = tid & 63, c = tid >> 6;
        int n = n0 + m;
        bool ok = (n < NN);
#pragma unroll
        for (int r = 0; r < 4; r++) {
            int k = c * 4 + r * 16;
            float4 v = ok ? *(const float4*)&agg[(size_t)n * 64 + k]
                          : make_float4(0.f, 0.f, 0.f, 0.f);
            xa[k + 0][m] = v.x; xa[k + 1][m] = v.y; xa[k + 2][m] = v.z; xa[k + 3][m] = v.w;
            float4 u = ok ? *(const float4*)&state[(size_t)n * 64 + k]
                          : make_float4(0.f, 0.f, 0.f, 0.f);
            xh[k + 0][m] = u.x; xh[k + 1][m] = u.y; xh[k + 2][m] = u.z; xh[k + 3][m] = u.w;
        }
#pragma unroll
        for (int r = 0; r < 12; r++) {
            int flat = r * 256 + tid;
            int k = flat / 48, col = flat % 48;
            int g = col >> 4, ci = col & 15;
            wiS[k][col] = Wih[(size_t)k * 192 + g * 64 + q * 16 + ci];
            whS[k][col] = Whh[(size_t)k * 192 + g * 64 + q * 16 + ci];
        }
    }
    __syncthreads();

    int ci = tid & 15, m4 = (tid >> 4) * 4;
    float gir[4] = {0,0,0,0}, giz[4] = {0,0,0,0}, gin[4] = {0,0,0,0};
    float ghr[4] = {0,0,0,0}, ghz[4] = {0,0,0,0}, ghn[4] = {0,0,0,0};

#pragma unroll 4
    for (int k = 0; k < 64; k++) {
        float4 xv = *(const float4*)&xa[k][m4];
        float4 hv = *(const float4*)&xh[k][m4];
        float wir = wiS[k][ci], wiz = wiS[k][16 + ci], win = wiS[k][32 + ci];
        float whr = whS[k][ci], whz = whS[k][16 + ci], whn = whS[k][32 + ci];
        gir[0] += xv.x * wir; gir[1] += xv.y * wir; gir[2] += xv.z * wir; gir[3] += xv.w * wir;
        giz[0] += xv.x * wiz; giz[1] += xv.y * wiz; giz[2] += xv.z * wiz; giz[3] += xv.w * wiz;
        gin[0] += xv.x * win; gin[1] += xv.y * win; gin[2] += xv.z * win; gin[3] += xv.w * win;
        ghr[0] += hv.x * whr; ghr[1] += hv.y * whr; ghr[2] += hv.z * whr; ghr[3] += hv.w * whr;
        ghz[0] += hv.x * whz; ghz[1] += hv.y * whz; ghz[2] += hv.z * whz; ghz[3] += hv.w * whz;
        ghn[0] += hv.x * whn; ghn[1] += hv.y * whn; ghn[2] += hv.z * whn; ghn[3] += hv.w * whn;
    }

    int c = q * 16 + ci;
    float bir = bih[c], biz = bih[64 + c], bin = bih[128 + c];
    float bhr = bhh[c], bhz = bhh[64 + c], bhn = bhh[128 + c];
#pragma unroll
    for (int i = 0; i < 4; i++) {
        int n = n0 + m4 + i;
        if (n < NN) {
            float hold = xh[c][m4 + i];
            float r = sigm(gir[i] + bir + ghr[i] + bhr);
            float z = sigm(giz[i] + biz + ghz[i] + bhz);
            float ng = tanhf(gin[i] + bin + r * (ghn[i] + bhn));
            stateNext[(size_t)n * 64 + c] = (1.f - z) * ng + z * hold;
            aggNext[(size_t)n * 64 + c] = 0.f;
        }
    }
}

__global__ __launch_bounds__(256) void out_proj(
    const float* __restrict__ state, const float* __restrict__ Wout,
    const float* __restrict__ bout, float* __restrict__ out)
{
    int n = blockIdx.x * 256 + threadIdx.x;
    if (n >= NN) return;
    float a0 = bout[0], a1 = bout[1];
    const float4* sr = (const float4*)(state + (size_t)n * 64);
#pragma unroll
    for (int t = 0; t < 16; t++) {
        float4 v = sr[t];
        a0 += v.x * Wout[2 * (4 * t + 0)] + v.y * Wout[2 * (4 * t + 1)]
            + v.z * Wout[2 * (4 * t + 2)] + v.w * Wout[2 * (4 * t + 3)];
        a1 += v.x * Wout[2 * (4 * t + 0) + 1] + v.y * Wout[2 * (4 * t + 1) + 1]
            + v.z * Wout[2 * (4 * t + 2) + 1] + v.w * Wout[2 * (4 * t + 3) + 1];
    }
    out[2 * n] = a0;
    out[2 * n + 1] = a1;
}

extern "C" void kernel_launch(void* const* d_in, const int* in_sizes, int n_in,
                              void* d_out, int out_size, void* d_ws, size_t ws_size,
                              hipStream_t stream)
{
    const int*   msg_node = (const int*)  d_in[0];
    const float* J_msg    = (const float*)d_in[1];
    const float* b        = (const float*)d_in[2];
    const float* W_in     = (const float*)d_in[4];
    const float* b_in     = (const float*)d_in[5];
    const float* W1       = (const float*)d_in[6];
    const float* b1       = (const float*)d_in[7];
    const float* W2       = (const float*)d_in[8];
    const float* b2       = (const float*)d_in[9];
    const float* W3       = (const float*)d_in[10];
    const float* b3       = (const float*)d_in[11];
    const float* W_ih     = (const float*)d_in[12];
    const float* b_ih     = (const float*)d_in[13];
    const float* W_hh     = (const float*)d_in[14];
    const float* b_hh     = (const float*)d_in[15];
    const float* W_out    = (const float*)d_in[16];
    const float* b_out    = (const float*)d_in[17];

    float* f      = (float*)d_ws;
    float* state0 = f;                                  // NN*64
    float* state1 = state0 + (size_t)NN * 64;           // NN*64
    float* agg0   = state1 + (size_t)NN * 64;           // NN*64
    float* agg1   = agg0   + (size_t)NN * 64;           // NN*64
    float* Pin    = agg1   + (size_t)NN * 64;           // NN*64
    float* Pout   = Pin    + (size_t)NN * 64;           // NN*64
    float* wf     = Pout   + (size_t)NN * 64;           // 192
    float* JP     = wf + 192;                           // NE
    int*   einP   = (int*)(JP + NE);                    // NE
    int*   eoutP  = einP + NE;                          // NE
    int*   cbase  = eoutP + NE;                         // NN
    int*   ccnt   = cbase + NN;                         // NN
    int*   ccur   = ccnt + NN;                          // NN
    int*   cbsum  = ccur + NN;                          // 512
    short* W2tB   = (short*)(cbsum + 512);              // 4096 bf16
    short* W3tB   = W2tB + 4096;                        // 4096 bf16

    float* stateBuf[2] = { state0, state1 };
    float* aggBuf[2]   = { agg0, agg1 };
    float* out = (float*)d_out;

    prep_wf<<<1, 64, 0, stream>>>(W1, wf);
    prep_w23<<<16, 256, 0, stream>>>(W2, W3, W2tB, W3tB);
    init_state<<<(NN * 64 + 255) / 256, 256, 0, stream>>>(b, W_in, b_in,
                                                          state0, agg0, agg1);

    csr_zero<<<(NN + 255) / 256, 256, 0, stream>>>(ccnt, ccur);
    csr_count<<<(NE + 255) / 256, 256, 0, stream>>>(msg_node, ccnt);
    scan_block<<<(NN + 255) / 256, 256, 0, stream>>>(ccnt, cbase, cbsum);
    scan_top<<<1, 256, 0, stream>>>(cbsum, (NN + 255) / 256);
    scan_add<<<(NN + 255) / 256, 256, 0, stream>>>(cbase, cbsum);
    csr_scatter_perm<<<(NE + 255) / 256, 256, 0, stream>>>(msg_node, J_msg, cbase, ccur,
                                                           einP, eoutP, JP);

    int ntile = (NN + 63) / 64;
    for (int p = 0; p < 3; p++) {
        float* sc = stateBuf[p & 1];
        float* sn = stateBuf[(p + 1) & 1];
        float* ac = aggBuf[p & 1];
        float* an = aggBuf[(p + 1) & 1];
        node_proj<<<ntile * 2, 256, 0, stream>>>(sc, b, W1, wf, b1, Pin, Pout);
        edge_msg_mfma<<<NE / 64, 256, 0, stream>>>(einP, eoutP, JP, Pin, Pout, wf,
                                                   W2tB, b2, W3tB, b3, ac);
        gru_fused<<<ntile * 4, 256, 0, stream>>>(ac, sc, W_ih, W_hh, b_ih, b_hh,
                                                 sn, an);
    }
    out_proj<<<(NN + 255) / 256, 256, 0, stream>>>(stateBuf[1], W_out, b_out, out);
}